// Round 4
// baseline (527.909 us; speedup 1.0000x reference)
//
#include <hip/hip_runtime.h>
#include <stdint.h>

#define N_NODES 50000
#define N_EDGES 800000
#define HF 128          // HEADS * OUT_F
#define NEG_SLOPE 0.2f
#define EPS_F 1e-8f

typedef __attribute__((ext_vector_type(8))) short short8;
typedef __attribute__((ext_vector_type(4))) float f32x4;

// ---------- helpers ----------
__device__ __forceinline__ float bf2f(unsigned short u) {
    union { unsigned int i; float f; } v; v.i = ((unsigned int)u) << 16; return v.f;
}
__device__ __forceinline__ unsigned short f2bf(float f) {
    union { unsigned int i; float f; } v; v.f = f;
    unsigned int b = v.i;
    unsigned int r = (b + 0x7FFFu + ((b >> 16) & 1u)) >> 16;   // round-to-nearest-even
    return (unsigned short)r;
}
__device__ __forceinline__ float leaky(float v) { return v > 0.f ? v : NEG_SLOPE * v; }
// order-preserving f32 -> u32 map (for atomicMax) and inverse
__device__ __forceinline__ unsigned int fmap(float f) {
    unsigned int b = __float_as_uint(f);
    return (b & 0x80000000u) ? ~b : (b | 0x80000000u);
}
__device__ __forceinline__ float funmap(unsigned int u) {
    unsigned int b = (u & 0x80000000u) ? (u & 0x7FFFFFFFu) : ~u;
    return __uint_as_float(b);
}

// ---------- K0: dtype sniff ----------
__global__ void k_sniff(const void* x, const void* eidx, int* flags) {
    int l = threadIdx.x;  // 64 threads
    const unsigned short* xu = (const unsigned short*)x;
    float f = bf2f(xu[2 * l]);
    float af = fabsf(f);
    bool extreme = !(af <= 1e6f) || (f != 0.0f && af < 1e-7f);
    unsigned long long mask = __ballot(extreme);
    const unsigned int* eu = (const unsigned int*)eidx;
    unsigned int w = eu[2 * l + 1];
    unsigned long long mask2 = __ballot(w != 0u);
    if (l == 0) {
        flags[0] = (__popcll(mask) >= 8) ? 0 : 1;   // 1 = bf16 floats
        flags[1] = (__popcll(mask2) >= 4) ? 0 : 1;  // 1 = int64 indices
    }
}

// ---------- K1: normalize W->bf16, a_src/a_dst->f32, edges->int32, fused degree count ----------
__global__ void k_convert(const void* W, const void* a_src, const void* a_dst, const void* eidx,
                          unsigned short* Wbf, float* af, int* srcI, int* dstI, int* counts,
                          const int* flags) {
    int i = blockIdx.x * blockDim.x + threadIdx.x;
    int isB = flags[0], is64 = flags[1];
    if (i < 16384) Wbf[i] = isB ? ((const unsigned short*)W)[i] : f2bf(((const float*)W)[i]);
    if (i < 128) {
        af[i]       = isB ? bf2f(((const unsigned short*)a_src)[i]) : ((const float*)a_src)[i];
        af[128 + i] = isB ? bf2f(((const unsigned short*)a_dst)[i]) : ((const float*)a_dst)[i];
    }
    if (i < N_EDGES) {
        int s, d;
        if (is64) {
            s = (int)((const long long*)eidx)[i];
            d = (int)((const long long*)eidx)[N_EDGES + i];
        } else {
            s = ((const int*)eidx)[i];
            d = ((const int*)eidx)[N_EDGES + i];
        }
        srcI[i] = s; dstI[i] = d;
        atomicAdd(&counts[d], 1);
    }
}

// ---------- K2: MFMA GEMM  h = x @ W^T (bf16), fused scores s_src/s_dst ----------
__global__ __launch_bounds__(256) void k_gemm(const void* x, const unsigned short* Wbf, const float* af,
                                              unsigned short* h, float* s_src, float* s_dst,
                                              const int* flags) {
    __shared__ short xl[64 * 136];    // [row][k] bf16, padded
    __shared__ short wl[128 * 136];   // [o][k] bf16, padded
    int tid = threadIdx.x;
    int isB = flags[0];
    int nb = blockIdx.x * 64;
    const unsigned short* xu = (const unsigned short*)x;
    const float* xf = (const float*)x;

    #pragma unroll
    for (int it = 0; it < 8; ++it) {
        int o = (tid >> 4) + it * 16;
        int k8 = (tid & 15) * 8;
        *(short8*)&wl[o * 136 + k8] = *(const short8*)&Wbf[o * 128 + k8];
    }
    #pragma unroll
    for (int it = 0; it < 4; ++it) {
        int row = (tid >> 4) + it * 16;
        int k8 = (tid & 15) * 8;
        int node = nb + row;
        short8 val;
        if (node < N_NODES) {
            if (isB) {
                val = *(const short8*)&xu[(size_t)node * 128 + k8];
            } else {
                float4 f0 = *(const float4*)&xf[(size_t)node * 128 + k8];
                float4 f1 = *(const float4*)&xf[(size_t)node * 128 + k8 + 4];
                val[0] = (short)f2bf(f0.x); val[1] = (short)f2bf(f0.y);
                val[2] = (short)f2bf(f0.z); val[3] = (short)f2bf(f0.w);
                val[4] = (short)f2bf(f1.x); val[5] = (short)f2bf(f1.y);
                val[6] = (short)f2bf(f1.z); val[7] = (short)f2bf(f1.w);
            }
        } else {
            val = short8{0,0,0,0,0,0,0,0};
        }
        *(short8*)&xl[row * 136 + k8] = val;
    }
    __syncthreads();

    int wv = tid >> 6, l = tid & 63;
    int lr = l & 15, lg = l >> 4;

    f32x4 acc0 = {0,0,0,0}, acc1 = {0,0,0,0}, acc2 = {0,0,0,0}, acc3 = {0,0,0,0};
    f32x4 acc4 = {0,0,0,0}, acc5 = {0,0,0,0}, acc6 = {0,0,0,0}, acc7 = {0,0,0,0};
    #pragma unroll
    for (int kb = 0; kb < 4; ++kb) {
        short8 a = *(const short8*)&xl[(wv * 16 + lr) * 136 + kb * 32 + lg * 8];
        short8 b0 = *(const short8*)&wl[(0 * 16 + lr) * 136 + kb * 32 + lg * 8];
        short8 b1 = *(const short8*)&wl[(1 * 16 + lr) * 136 + kb * 32 + lg * 8];
        short8 b2 = *(const short8*)&wl[(2 * 16 + lr) * 136 + kb * 32 + lg * 8];
        short8 b3 = *(const short8*)&wl[(3 * 16 + lr) * 136 + kb * 32 + lg * 8];
        short8 b4 = *(const short8*)&wl[(4 * 16 + lr) * 136 + kb * 32 + lg * 8];
        short8 b5 = *(const short8*)&wl[(5 * 16 + lr) * 136 + kb * 32 + lg * 8];
        short8 b6 = *(const short8*)&wl[(6 * 16 + lr) * 136 + kb * 32 + lg * 8];
        short8 b7 = *(const short8*)&wl[(7 * 16 + lr) * 136 + kb * 32 + lg * 8];
        acc0 = __builtin_amdgcn_mfma_f32_16x16x32_bf16(a, b0, acc0, 0, 0, 0);
        acc1 = __builtin_amdgcn_mfma_f32_16x16x32_bf16(a, b1, acc1, 0, 0, 0);
        acc2 = __builtin_amdgcn_mfma_f32_16x16x32_bf16(a, b2, acc2, 0, 0, 0);
        acc3 = __builtin_amdgcn_mfma_f32_16x16x32_bf16(a, b3, acc3, 0, 0, 0);
        acc4 = __builtin_amdgcn_mfma_f32_16x16x32_bf16(a, b4, acc4, 0, 0, 0);
        acc5 = __builtin_amdgcn_mfma_f32_16x16x32_bf16(a, b5, acc5, 0, 0, 0);
        acc6 = __builtin_amdgcn_mfma_f32_16x16x32_bf16(a, b6, acc6, 0, 0, 0);
        acc7 = __builtin_amdgcn_mfma_f32_16x16x32_bf16(a, b7, acc7, 0, 0, 0);
    }

    float pS[4][4], pD[4][4];
    #pragma unroll
    for (int r = 0; r < 4; ++r)
        #pragma unroll
        for (int hd = 0; hd < 4; ++hd) { pS[r][hd] = 0.f; pD[r][hd] = 0.f; }

    #define EPI(OT, ACC) { \
        float aSv = af[(OT) * 16 + lr]; \
        float aDv = af[128 + (OT) * 16 + lr]; \
        _Pragma("unroll") \
        for (int r = 0; r < 4; ++r) { \
            int n = nb + wv * 16 + lg * 4 + r; \
            float v = ACC[r]; \
            if (n < N_NODES) h[(size_t)n * HF + (OT) * 16 + lr] = f2bf(v); \
            pS[r][(OT) >> 1] += v * aSv; \
            pD[r][(OT) >> 1] += v * aDv; \
        } }
    EPI(0, acc0) EPI(1, acc1) EPI(2, acc2) EPI(3, acc3)
    EPI(4, acc4) EPI(5, acc5) EPI(6, acc6) EPI(7, acc7)
    #undef EPI

    #pragma unroll
    for (int off = 1; off < 16; off <<= 1) {
        #pragma unroll
        for (int r = 0; r < 4; ++r)
            #pragma unroll
            for (int hd = 0; hd < 4; ++hd) {
                pS[r][hd] += __shfl_xor(pS[r][hd], off, 64);
                pD[r][hd] += __shfl_xor(pD[r][hd], off, 64);
            }
    }
    if (lr == 0) {
        #pragma unroll
        for (int r = 0; r < 4; ++r) {
            int n = nb + wv * 16 + lg * 4 + r;
            if (n < N_NODES) {
                #pragma unroll
                for (int hd = 0; hd < 4; ++hd) {
                    s_src[n * 4 + hd] = pS[r][hd];
                    s_dst[n * 4 + hd] = pD[r][hd];
                }
            }
        }
    }
}

// ---------- K4a/b/c: coalesced 3-phase exclusive scan ----------
__global__ __launch_bounds__(1024) void k_scan1(const int* counts, int* row_start, int* btot) {
    __shared__ int buf[1024];
    int t = threadIdx.x;
    int i = blockIdx.x * 1024 + t;
    int c = (i < N_NODES) ? counts[i] : 0;
    buf[t] = c;
    __syncthreads();
    for (int off = 1; off < 1024; off <<= 1) {
        int v = (t >= off) ? buf[t - off] : 0;
        __syncthreads();
        buf[t] += v;
        __syncthreads();
    }
    if (i < N_NODES) row_start[i] = buf[t] - c;
    if (t == 1023) btot[blockIdx.x] = buf[1023];
}
__global__ void k_scan2(int* btot, int* row_start, int nblk) {
    int l = threadIdx.x;  // 64 threads
    int v = (l < nblk) ? btot[l] : 0;
    int inc = v;
    for (int off = 1; off < 64; off <<= 1) {
        int u = __shfl_up(inc, off, 64);
        if (l >= off) inc += u;
    }
    int tot = __shfl(inc, nblk - 1, 64);
    if (l < nblk) btot[l] = inc - v;
    if (l == 0) row_start[N_NODES] = tot;
}
__global__ __launch_bounds__(1024) void k_scan3(int* row_start, const int* btot) {
    int i = blockIdx.x * 1024 + threadIdx.x;
    if (i < N_NODES) row_start[i] += btot[blockIdx.x];
}

// ---------- K5: scatter packed (src|dst<<16) into CSR + fused leaky-score atomicMax ----------
__global__ void k_scatter(const int* srcI, const int* dstI, const int* row_start, int* cursor,
                          unsigned int* csr, const float* s_src, const float* s_dst,
                          unsigned int* nodeMax) {
    int i = blockIdx.x * blockDim.x + threadIdx.x;
    if (i >= N_EDGES) return;
    int s = srcI[i], d = dstI[i];
    int p = atomicAdd(&cursor[d], 1);
    csr[row_start[d] + p] = (unsigned int)s | ((unsigned int)d << 16);
    float4 ss = *(const float4*)&s_src[s * 4];
    float4 sd = *(const float4*)&s_dst[d * 4];
    atomicMax(&nodeMax[d * 4 + 0], fmap(leaky(ss.x + sd.x)));
    atomicMax(&nodeMax[d * 4 + 1], fmap(leaky(ss.y + sd.y)));
    atomicMax(&nodeMax[d * 4 + 2], fmap(leaky(ss.z + sd.z)));
    atomicMax(&nodeMax[d * 4 + 3], fmap(leaky(ss.w + sd.w)));
}

// ---------- K6: edge-parallel exp + sum-atomics + unnormalized weights ----------
__global__ void k_wts2(const unsigned int* csr, const float* s_src, const float* s_dst,
                       const unsigned int* nodeMax, float* nodeSum, float* wbuf) {
    int i = blockIdx.x * blockDim.x + threadIdx.x;
    if (i >= N_EDGES) return;
    unsigned int pk = csr[i];
    int s = (int)(pk & 0xFFFFu), d = (int)(pk >> 16);
    float4 ss = *(const float4*)&s_src[s * 4];
    float4 sd = *(const float4*)&s_dst[d * 4];
    float e0 = __expf(leaky(ss.x + sd.x) - funmap(nodeMax[d * 4 + 0]));
    float e1 = __expf(leaky(ss.y + sd.y) - funmap(nodeMax[d * 4 + 1]));
    float e2 = __expf(leaky(ss.z + sd.z) - funmap(nodeMax[d * 4 + 2]));
    float e3 = __expf(leaky(ss.w + sd.w) - funmap(nodeMax[d * 4 + 3]));
    atomicAdd(&nodeSum[d * 4 + 0], e0);
    atomicAdd(&nodeSum[d * 4 + 1], e1);
    atomicAdd(&nodeSum[d * 4 + 2], e2);
    atomicAdd(&nodeSum[d * 4 + 3], e3);
    *(float4*)&wbuf[(size_t)i * 4] = make_float4(e0, e1, e2, e3);
}

// ---------- K7: pure gather-FMA aggregation (1 wave = 1 node, 4 edges/iter) ----------
__global__ __launch_bounds__(256) void k_agg(const unsigned short* h, const float* nodeSum,
                                             const int* row_start, const unsigned int* csr,
                                             const float* wbuf, float* out) {
    int wid = threadIdx.x >> 6;
    int l = threadIdx.x & 63;
    int n = blockIdx.x * 4 + wid;
    if (n >= N_NODES) return;
    int rs = row_start[n];
    int deg = row_start[n + 1] - rs;
    int lf = l & 15;           // feature block: features lf*8 .. lf*8+7
    int grp = l >> 4;          // edge sub-slot 0..3
    int hd = lf >> 2;          // head of this feature block
    if (deg == 0) {
        *(float2*)&out[(size_t)n * HF + lf * 8 + grp * 2] = make_float2(0.f, 0.f);
        return;
    }
    float inv = 1.0f / (nodeSum[n * 4 + hd] + EPS_F);
    float a0=0,a1=0,a2=0,a3=0,a4=0,a5=0,a6=0,a7=0;

    // 1-deep software pipeline
    unsigned int pk = 0; float w = 0.f;
    if (grp < deg) {
        pk = csr[rs + grp];
        w = wbuf[(size_t)(rs + grp) * 4 + hd] * inv;
    }
    uint4 u = *(const uint4*)&h[(size_t)(pk & 0xFFFFu) * HF + lf * 8];

    for (int it = 0; it < deg; it += 4) {
        int e1 = it + 4 + grp;
        unsigned int pk1 = 0; float w1 = 0.f;
        if (e1 < deg) {
            pk1 = csr[rs + e1];
            w1 = wbuf[(size_t)(rs + e1) * 4 + hd] * inv;
        }
        uint4 u1 = *(const uint4*)&h[(size_t)(pk1 & 0xFFFFu) * HF + lf * 8];
        a0 += w * bf2f((unsigned short)(u.x & 0xFFFFu)); a1 += w * bf2f((unsigned short)(u.x >> 16));
        a2 += w * bf2f((unsigned short)(u.y & 0xFFFFu)); a3 += w * bf2f((unsigned short)(u.y >> 16));
        a4 += w * bf2f((unsigned short)(u.z & 0xFFFFu)); a5 += w * bf2f((unsigned short)(u.z >> 16));
        a6 += w * bf2f((unsigned short)(u.w & 0xFFFFu)); a7 += w * bf2f((unsigned short)(u.w >> 16));
        pk = pk1; w = w1; u = u1;
    }
    // reduce across the 4 edge-groups (lane bits 4,5)
    #pragma unroll
    for (int off = 16; off <= 32; off <<= 1) {
        a0 += __shfl_xor(a0, off, 64); a1 += __shfl_xor(a1, off, 64);
        a2 += __shfl_xor(a2, off, 64); a3 += __shfl_xor(a3, off, 64);
        a4 += __shfl_xor(a4, off, 64); a5 += __shfl_xor(a5, off, 64);
        a6 += __shfl_xor(a6, off, 64); a7 += __shfl_xor(a7, off, 64);
    }
    if (grp == 0) *(float4*)&out[(size_t)n * HF + lf * 8]     = make_float4(a0, a1, a2, a3);
    if (grp == 1) *(float4*)&out[(size_t)n * HF + lf * 8 + 4] = make_float4(a4, a5, a6, a7);
}

extern "C" void kernel_launch(void* const* d_in, const int* in_sizes, int n_in,
                              void* d_out, int out_size, void* d_ws, size_t ws_size,
                              hipStream_t stream) {
    const void* x     = d_in[0];
    const void* eidx  = d_in[1];
    const void* W     = d_in[2];
    const void* a_src = d_in[3];
    const void* a_dst = d_in[4];
    char* ws = (char*)d_ws;

    size_t off = 0;
    auto alloc = [&](size_t bytes) { size_t o = off; off += (bytes + 255) & ~(size_t)255; return o; };
    size_t flagsO  = alloc(64 * 4);
    size_t countsO = alloc((size_t)N_NODES * 4);
    size_t cursorO = alloc((size_t)N_NODES * 4);
    size_t nmaxO   = alloc((size_t)N_NODES * 4 * 4);
    size_t nsumO   = alloc((size_t)N_NODES * 4 * 4);
    size_t zeroEnd = off;                       // [countsO, zeroEnd) memset 0
    size_t rowO    = alloc((size_t)(N_NODES + 1) * 4);
    size_t btotO   = alloc(64 * 4);
    size_t srcO    = alloc((size_t)N_EDGES * 4);
    size_t dstO    = alloc((size_t)N_EDGES * 4);
    size_t csrO    = alloc((size_t)N_EDGES * 4);
    size_t wbufO   = alloc((size_t)N_EDGES * 4 * 4);
    size_t WbO     = alloc(16384 * 2);
    size_t afO     = alloc(256 * 4);
    size_t ssO     = alloc((size_t)N_NODES * 4 * 4);
    size_t sdO     = alloc((size_t)N_NODES * 4 * 4);
    size_t hO      = alloc((size_t)N_NODES * HF * 2);
    (void)ws_size; (void)in_sizes; (void)n_in;

    int*   flags   = (int*)(ws + flagsO);
    int*   counts  = (int*)(ws + countsO);
    int*   cursor  = (int*)(ws + cursorO);
    unsigned int* nodeMax = (unsigned int*)(ws + nmaxO);
    float* nodeSum = (float*)(ws + nsumO);
    int*   rowSt   = (int*)(ws + rowO);
    int*   btot    = (int*)(ws + btotO);
    int*   srcI    = (int*)(ws + srcO);
    int*   dstI    = (int*)(ws + dstO);
    unsigned int* csrP = (unsigned int*)(ws + csrO);
    float* wbuf    = (float*)(ws + wbufO);
    unsigned short* Wbf = (unsigned short*)(ws + WbO);
    float* af      = (float*)(ws + afO);
    float* s_src   = (float*)(ws + ssO);
    float* s_dst   = (float*)(ws + sdO);
    unsigned short* h = (unsigned short*)(ws + hO);
    float* outF    = (float*)d_out;

    hipMemsetAsync(ws + countsO, 0, zeroEnd - countsO, stream);

    const int SCAN_BLKS = (N_NODES + 1023) / 1024;   // 49
    k_sniff<<<1, 64, 0, stream>>>(x, eidx, flags);
    k_convert<<<(N_EDGES + 255) / 256, 256, 0, stream>>>(W, a_src, a_dst, eidx, Wbf, af, srcI, dstI, counts, flags);
    k_gemm<<<(N_NODES + 63) / 64, 256, 0, stream>>>(x, Wbf, af, h, s_src, s_dst, flags);
    k_scan1<<<SCAN_BLKS, 1024, 0, stream>>>(counts, rowSt, btot);
    k_scan2<<<1, 64, 0, stream>>>(btot, rowSt, SCAN_BLKS);
    k_scan3<<<SCAN_BLKS, 1024, 0, stream>>>(rowSt, btot);
    k_scatter<<<(N_EDGES + 255) / 256, 256, 0, stream>>>(srcI, dstI, rowSt, cursor, csrP, s_src, s_dst, nodeMax);
    k_wts2<<<(N_EDGES + 255) / 256, 256, 0, stream>>>(csrP, s_src, s_dst, nodeMax, nodeSum, wbuf);
    k_agg<<<(N_NODES + 3) / 4, 256, 0, stream>>>(h, nodeSum, rowSt, csrP, wbuf, outF);
}

// Round 5
// 223.599 us; speedup vs baseline: 2.3610x; 2.3610x over previous
//
#include <hip/hip_runtime.h>
#include <stdint.h>

#define N_NODES 50000
#define N_EDGES 800000
#define HF 128          // HEADS * OUT_F
#define NEG_SLOPE 0.2f
#define EPS_F 1e-8f

typedef __attribute__((ext_vector_type(8))) short short8;
typedef __attribute__((ext_vector_type(4))) float f32x4;

// ---------- helpers ----------
__device__ __forceinline__ float bf2f(unsigned short u) {
    union { unsigned int i; float f; } v; v.i = ((unsigned int)u) << 16; return v.f;
}
__device__ __forceinline__ unsigned short f2bf(float f) {
    union { unsigned int i; float f; } v; v.f = f;
    unsigned int b = v.i;
    unsigned int r = (b + 0x7FFFu + ((b >> 16) & 1u)) >> 16;   // round-to-nearest-even
    return (unsigned short)r;
}
__device__ __forceinline__ float leaky(float v) { return v > 0.f ? v : NEG_SLOPE * v; }

// ---------- K0: dtype sniff ----------
__global__ void k_sniff(const void* x, const void* eidx, int* flags) {
    int l = threadIdx.x;  // 64 threads
    const unsigned short* xu = (const unsigned short*)x;
    float f = bf2f(xu[2 * l]);
    float af = fabsf(f);
    bool extreme = !(af <= 1e6f) || (f != 0.0f && af < 1e-7f);
    unsigned long long mask = __ballot(extreme);
    const unsigned int* eu = (const unsigned int*)eidx;
    unsigned int w = eu[2 * l + 1];
    unsigned long long mask2 = __ballot(w != 0u);
    if (l == 0) {
        flags[0] = (__popcll(mask) >= 8) ? 0 : 1;   // 1 = bf16 floats
        flags[1] = (__popcll(mask2) >= 4) ? 0 : 1;  // 1 = int64 indices
    }
}

// ---------- K1: normalize W->bf16, a_src/a_dst->f32, edges->int32, fused degree count ----------
__global__ void k_convert(const void* W, const void* a_src, const void* a_dst, const void* eidx,
                          unsigned short* Wbf, float* af, int* srcI, int* dstI, int* counts,
                          const int* flags) {
    int i = blockIdx.x * blockDim.x + threadIdx.x;
    int isB = flags[0], is64 = flags[1];
    if (i < 16384) Wbf[i] = isB ? ((const unsigned short*)W)[i] : f2bf(((const float*)W)[i]);
    if (i < 128) {
        af[i]       = isB ? bf2f(((const unsigned short*)a_src)[i]) : ((const float*)a_src)[i];
        af[128 + i] = isB ? bf2f(((const unsigned short*)a_dst)[i]) : ((const float*)a_dst)[i];
    }
    if (i < N_EDGES) {
        int s, d;
        if (is64) {
            s = (int)((const long long*)eidx)[i];
            d = (int)((const long long*)eidx)[N_EDGES + i];
        } else {
            s = ((const int*)eidx)[i];
            d = ((const int*)eidx)[N_EDGES + i];
        }
        srcI[i] = s; dstI[i] = d;
        atomicAdd(&counts[d], 1);
    }
}

// ---------- K2: MFMA GEMM  h = x @ W^T (bf16), fused scores s_src/s_dst ----------
__global__ __launch_bounds__(256) void k_gemm(const void* x, const unsigned short* Wbf, const float* af,
                                              unsigned short* h, float* s_src, float* s_dst,
                                              const int* flags) {
    __shared__ short xl[64 * 136];    // [row][k] bf16, padded
    __shared__ short wl[128 * 136];   // [o][k] bf16, padded
    int tid = threadIdx.x;
    int isB = flags[0];
    int nb = blockIdx.x * 64;
    const unsigned short* xu = (const unsigned short*)x;
    const float* xf = (const float*)x;

    #pragma unroll
    for (int it = 0; it < 8; ++it) {
        int o = (tid >> 4) + it * 16;
        int k8 = (tid & 15) * 8;
        *(short8*)&wl[o * 136 + k8] = *(const short8*)&Wbf[o * 128 + k8];
    }
    #pragma unroll
    for (int it = 0; it < 4; ++it) {
        int row = (tid >> 4) + it * 16;
        int k8 = (tid & 15) * 8;
        int node = nb + row;
        short8 val;
        if (node < N_NODES) {
            if (isB) {
                val = *(const short8*)&xu[(size_t)node * 128 + k8];
            } else {
                float4 f0 = *(const float4*)&xf[(size_t)node * 128 + k8];
                float4 f1 = *(const float4*)&xf[(size_t)node * 128 + k8 + 4];
                val[0] = (short)f2bf(f0.x); val[1] = (short)f2bf(f0.y);
                val[2] = (short)f2bf(f0.z); val[3] = (short)f2bf(f0.w);
                val[4] = (short)f2bf(f1.x); val[5] = (short)f2bf(f1.y);
                val[6] = (short)f2bf(f1.z); val[7] = (short)f2bf(f1.w);
            }
        } else {
            val = short8{0,0,0,0,0,0,0,0};
        }
        *(short8*)&xl[row * 136 + k8] = val;
    }
    __syncthreads();

    int wv = tid >> 6, l = tid & 63;
    int lr = l & 15, lg = l >> 4;

    f32x4 acc0 = {0,0,0,0}, acc1 = {0,0,0,0}, acc2 = {0,0,0,0}, acc3 = {0,0,0,0};
    f32x4 acc4 = {0,0,0,0}, acc5 = {0,0,0,0}, acc6 = {0,0,0,0}, acc7 = {0,0,0,0};
    #pragma unroll
    for (int kb = 0; kb < 4; ++kb) {
        short8 a = *(const short8*)&xl[(wv * 16 + lr) * 136 + kb * 32 + lg * 8];
        short8 b0 = *(const short8*)&wl[(0 * 16 + lr) * 136 + kb * 32 + lg * 8];
        short8 b1 = *(const short8*)&wl[(1 * 16 + lr) * 136 + kb * 32 + lg * 8];
        short8 b2 = *(const short8*)&wl[(2 * 16 + lr) * 136 + kb * 32 + lg * 8];
        short8 b3 = *(const short8*)&wl[(3 * 16 + lr) * 136 + kb * 32 + lg * 8];
        short8 b4 = *(const short8*)&wl[(4 * 16 + lr) * 136 + kb * 32 + lg * 8];
        short8 b5 = *(const short8*)&wl[(5 * 16 + lr) * 136 + kb * 32 + lg * 8];
        short8 b6 = *(const short8*)&wl[(6 * 16 + lr) * 136 + kb * 32 + lg * 8];
        short8 b7 = *(const short8*)&wl[(7 * 16 + lr) * 136 + kb * 32 + lg * 8];
        acc0 = __builtin_amdgcn_mfma_f32_16x16x32_bf16(a, b0, acc0, 0, 0, 0);
        acc1 = __builtin_amdgcn_mfma_f32_16x16x32_bf16(a, b1, acc1, 0, 0, 0);
        acc2 = __builtin_amdgcn_mfma_f32_16x16x32_bf16(a, b2, acc2, 0, 0, 0);
        acc3 = __builtin_amdgcn_mfma_f32_16x16x32_bf16(a, b3, acc3, 0, 0, 0);
        acc4 = __builtin_amdgcn_mfma_f32_16x16x32_bf16(a, b4, acc4, 0, 0, 0);
        acc5 = __builtin_amdgcn_mfma_f32_16x16x32_bf16(a, b5, acc5, 0, 0, 0);
        acc6 = __builtin_amdgcn_mfma_f32_16x16x32_bf16(a, b6, acc6, 0, 0, 0);
        acc7 = __builtin_amdgcn_mfma_f32_16x16x32_bf16(a, b7, acc7, 0, 0, 0);
    }

    float pS[4][4], pD[4][4];
    #pragma unroll
    for (int r = 0; r < 4; ++r)
        #pragma unroll
        for (int hd = 0; hd < 4; ++hd) { pS[r][hd] = 0.f; pD[r][hd] = 0.f; }

    #define EPI(OT, ACC) { \
        float aSv = af[(OT) * 16 + lr]; \
        float aDv = af[128 + (OT) * 16 + lr]; \
        _Pragma("unroll") \
        for (int r = 0; r < 4; ++r) { \
            int n = nb + wv * 16 + lg * 4 + r; \
            float v = ACC[r]; \
            if (n < N_NODES) h[(size_t)n * HF + (OT) * 16 + lr] = f2bf(v); \
            pS[r][(OT) >> 1] += v * aSv; \
            pD[r][(OT) >> 1] += v * aDv; \
        } }
    EPI(0, acc0) EPI(1, acc1) EPI(2, acc2) EPI(3, acc3)
    EPI(4, acc4) EPI(5, acc5) EPI(6, acc6) EPI(7, acc7)
    #undef EPI

    #pragma unroll
    for (int off = 1; off < 16; off <<= 1) {
        #pragma unroll
        for (int r = 0; r < 4; ++r)
            #pragma unroll
            for (int hd = 0; hd < 4; ++hd) {
                pS[r][hd] += __shfl_xor(pS[r][hd], off, 64);
                pD[r][hd] += __shfl_xor(pD[r][hd], off, 64);
            }
    }
    if (lr == 0) {
        #pragma unroll
        for (int r = 0; r < 4; ++r) {
            int n = nb + wv * 16 + lg * 4 + r;
            if (n < N_NODES) {
                #pragma unroll
                for (int hd = 0; hd < 4; ++hd) {
                    s_src[n * 4 + hd] = pS[r][hd];
                    s_dst[n * 4 + hd] = pD[r][hd];
                }
            }
        }
    }
}

// ---------- K4a/b/c: coalesced 3-phase exclusive scan ----------
__global__ __launch_bounds__(1024) void k_scan1(const int* counts, int* row_start, int* btot) {
    __shared__ int buf[1024];
    int t = threadIdx.x;
    int i = blockIdx.x * 1024 + t;
    int c = (i < N_NODES) ? counts[i] : 0;
    buf[t] = c;
    __syncthreads();
    for (int off = 1; off < 1024; off <<= 1) {
        int v = (t >= off) ? buf[t - off] : 0;
        __syncthreads();
        buf[t] += v;
        __syncthreads();
    }
    if (i < N_NODES) row_start[i] = buf[t] - c;
    if (t == 1023) btot[blockIdx.x] = buf[1023];
}
__global__ void k_scan2(int* btot, int* row_start, int nblk) {
    int l = threadIdx.x;  // 64 threads
    int v = (l < nblk) ? btot[l] : 0;
    int inc = v;
    for (int off = 1; off < 64; off <<= 1) {
        int u = __shfl_up(inc, off, 64);
        if (l >= off) inc += u;
    }
    int tot = __shfl(inc, nblk - 1, 64);
    if (l < nblk) btot[l] = inc - v;
    if (l == 0) row_start[N_NODES] = tot;
}
__global__ __launch_bounds__(1024) void k_scan3(int* row_start, const int* btot) {
    int i = blockIdx.x * 1024 + threadIdx.x;
    if (i < N_NODES) row_start[i] += btot[blockIdx.x];
}

// ---------- K5: scatter src id + leaky scores into CSR slots (no float atomics) ----------
__global__ void k_scatter(const int* srcI, const int* dstI, const int* row_start, int* cursor,
                          int* csr, const float* s_src, const float* s_dst, float* sbuf) {
    int i = blockIdx.x * blockDim.x + threadIdx.x;
    if (i >= N_EDGES) return;
    int s = srcI[i], d = dstI[i];
    int p = atomicAdd(&cursor[d], 1);
    int slot = row_start[d] + p;
    csr[slot] = s;
    float4 ss = *(const float4*)&s_src[s * 4];
    float4 sd = *(const float4*)&s_dst[d * 4];
    *(float4*)&sbuf[(size_t)slot * 4] =
        make_float4(leaky(ss.x + sd.x), leaky(ss.y + sd.y),
                    leaky(ss.z + sd.z), leaky(ss.w + sd.w));
}

// ---------- K6: gather-FMA aggregation with inline softmax (1 wave = 1 node) ----------
// lane split: lf = l&15 (feature octet lf*8..lf*8+7), grp = l>>4 (edge subset), hd = lf>>2.
__global__ __launch_bounds__(256) void k_agg(const unsigned short* h, const float* sbuf,
                                             const int* row_start, const int* csr, float* out) {
    int wid = threadIdx.x >> 6;
    int l = threadIdx.x & 63;
    int n = blockIdx.x * 4 + wid;
    if (n >= N_NODES) return;
    int rs = row_start[n];
    int deg = row_start[n + 1] - rs;
    int lf = l & 15, grp = l >> 4, hd = lf >> 2;
    if (deg == 0) {
        *(float2*)&out[(size_t)n * HF + lf * 8 + grp * 2] = make_float2(0.f, 0.f);
        return;
    }
    const float NI = -__builtin_inff();

    // pass 1: per-head segment max (contiguous dword reads, 2 shuffles)
    float m = NI;
    for (int e = grp; e < deg; e += 4) m = fmaxf(m, sbuf[(size_t)(rs + e) * 4 + hd]);
    m = fmaxf(m, __shfl_xor(m, 16, 64));
    m = fmaxf(m, __shfl_xor(m, 32, 64));

    // pass 2: gather h, weight by exp(s-m), accumulate z and unnormalized out
    float z = 0.f;
    float a0=0,a1=0,a2=0,a3=0,a4=0,a5=0,a6=0,a7=0;
    float sc = NI; int si = 0;
    if (grp < deg) { sc = sbuf[(size_t)(rs + grp) * 4 + hd]; si = csr[rs + grp]; }
    uint4 u = *(const uint4*)&h[(size_t)si * HF + lf * 8];

    for (int it = 0; it < deg; it += 4) {
        int e1 = it + 4 + grp;
        float sc1 = NI; int si1 = 0;
        if (e1 < deg) { sc1 = sbuf[(size_t)(rs + e1) * 4 + hd]; si1 = csr[rs + e1]; }
        uint4 u1 = *(const uint4*)&h[(size_t)si1 * HF + lf * 8];
        float w = __expf(sc - m);          // 0 for invalid slots (sc = -inf)
        z += w;
        a0 += w * bf2f((unsigned short)(u.x & 0xFFFFu)); a1 += w * bf2f((unsigned short)(u.x >> 16));
        a2 += w * bf2f((unsigned short)(u.y & 0xFFFFu)); a3 += w * bf2f((unsigned short)(u.y >> 16));
        a4 += w * bf2f((unsigned short)(u.z & 0xFFFFu)); a5 += w * bf2f((unsigned short)(u.z >> 16));
        a6 += w * bf2f((unsigned short)(u.w & 0xFFFFu)); a7 += w * bf2f((unsigned short)(u.w >> 16));
        sc = sc1; si = si1; u = u1;
    }
    // reduce z and acc across the 4 edge-groups (lane bits 4,5)
    #pragma unroll
    for (int off = 16; off <= 32; off <<= 1) {
        z  += __shfl_xor(z,  off, 64);
        a0 += __shfl_xor(a0, off, 64); a1 += __shfl_xor(a1, off, 64);
        a2 += __shfl_xor(a2, off, 64); a3 += __shfl_xor(a3, off, 64);
        a4 += __shfl_xor(a4, off, 64); a5 += __shfl_xor(a5, off, 64);
        a6 += __shfl_xor(a6, off, 64); a7 += __shfl_xor(a7, off, 64);
    }
    float inv = 1.0f / (z + EPS_F);
    if (grp == 0) *(float4*)&out[(size_t)n * HF + lf * 8]     = make_float4(a0*inv, a1*inv, a2*inv, a3*inv);
    if (grp == 1) *(float4*)&out[(size_t)n * HF + lf * 8 + 4] = make_float4(a4*inv, a5*inv, a6*inv, a7*inv);
}

extern "C" void kernel_launch(void* const* d_in, const int* in_sizes, int n_in,
                              void* d_out, int out_size, void* d_ws, size_t ws_size,
                              hipStream_t stream) {
    const void* x     = d_in[0];
    const void* eidx  = d_in[1];
    const void* W     = d_in[2];
    const void* a_src = d_in[3];
    const void* a_dst = d_in[4];
    char* ws = (char*)d_ws;

    size_t off = 0;
    auto alloc = [&](size_t bytes) { size_t o = off; off += (bytes + 255) & ~(size_t)255; return o; };
    size_t flagsO  = alloc(64 * 4);
    size_t countsO = alloc((size_t)N_NODES * 4);
    size_t cursorO = alloc((size_t)N_NODES * 4);
    size_t zeroEnd = off;                       // [countsO, zeroEnd) memset 0
    size_t rowO    = alloc((size_t)(N_NODES + 1) * 4);
    size_t btotO   = alloc(64 * 4);
    size_t srcO    = alloc((size_t)N_EDGES * 4);
    size_t dstO    = alloc((size_t)N_EDGES * 4);
    size_t csrO    = alloc((size_t)N_EDGES * 4);
    size_t sbufO   = alloc((size_t)N_EDGES * 4 * 4);
    size_t WbO     = alloc(16384 * 2);
    size_t afO     = alloc(256 * 4);
    size_t ssO     = alloc((size_t)N_NODES * 4 * 4);
    size_t sdO     = alloc((size_t)N_NODES * 4 * 4);
    size_t hO      = alloc((size_t)N_NODES * HF * 2);
    (void)ws_size; (void)in_sizes; (void)n_in;

    int*   flags   = (int*)(ws + flagsO);
    int*   counts  = (int*)(ws + countsO);
    int*   cursor  = (int*)(ws + cursorO);
    int*   rowSt   = (int*)(ws + rowO);
    int*   btot    = (int*)(ws + btotO);
    int*   srcI    = (int*)(ws + srcO);
    int*   dstI    = (int*)(ws + dstO);
    int*   csrS    = (int*)(ws + csrO);
    float* sbuf    = (float*)(ws + sbufO);
    unsigned short* Wbf = (unsigned short*)(ws + WbO);
    float* af      = (float*)(ws + afO);
    float* s_src   = (float*)(ws + ssO);
    float* s_dst   = (float*)(ws + sdO);
    unsigned short* h = (unsigned short*)(ws + hO);
    float* outF    = (float*)d_out;

    hipMemsetAsync(ws + countsO, 0, zeroEnd - countsO, stream);

    const int SCAN_BLKS = (N_NODES + 1023) / 1024;   // 49
    k_sniff<<<1, 64, 0, stream>>>(x, eidx, flags);
    k_convert<<<(N_EDGES + 255) / 256, 256, 0, stream>>>(W, a_src, a_dst, eidx, Wbf, af, srcI, dstI, counts, flags);
    k_gemm<<<(N_NODES + 63) / 64, 256, 0, stream>>>(x, Wbf, af, h, s_src, s_dst, flags);
    k_scan1<<<SCAN_BLKS, 1024, 0, stream>>>(counts, rowSt, btot);
    k_scan2<<<1, 64, 0, stream>>>(btot, rowSt, SCAN_BLKS);
    k_scan3<<<SCAN_BLKS, 1024, 0, stream>>>(rowSt, btot);
    k_scatter<<<(N_EDGES + 255) / 256, 256, 0, stream>>>(srcI, dstI, rowSt, cursor, csrS, s_src, s_dst, sbuf);
    k_agg<<<(N_NODES + 3) / 4, 256, 0, stream>>>(h, sbuf, rowSt, csrS, outF);
}